// Round 5
// baseline (8229.668 us; speedup 1.0000x reference)
//
#include <hip/hip_runtime.h>
#include <hip/hip_bf16.h>

// ---------------------------------------------------------------------------
// conv1d embed -> LSTM encoder (512 steps, B=64, H=512) -> attention decoder
// (48 steps) -> projection.
// Sync: fence-free slot barriers; cross-block mutable data via relaxed
// agent-scope atomics; producer drains vmcnt before publishing.
// Decoder: 2 full barriers/step + one-way hwh handoff (producers publish
// per-block slots; consumers poll). hWh computed from h_t AFTER h assembly
// (round-4 bug fix). fc(t-1) overlaps the hwh wait on Q blocks.
// ---------------------------------------------------------------------------

typedef short bf16x8 __attribute__((ext_vector_type(8)));
typedef float f32x4 __attribute__((ext_vector_type(4)));

static __device__ __forceinline__ float bf2f(unsigned short u){
  return __uint_as_float(((unsigned)u) << 16);
}
static __device__ __forceinline__ unsigned short f2bf(float f){
  unsigned x = __float_as_uint(f);
  return (unsigned short)((x + 0x7fffu + ((x >> 16) & 1u)) >> 16);   // RNE
}
static __device__ __forceinline__ float sigm(float x){
  return __builtin_amdgcn_rcpf(1.f + __builtin_amdgcn_exp2f(-1.44269504f*x));
}
static __device__ __forceinline__ float tanh2(float x){
  return 1.f - 2.f*__builtin_amdgcn_rcpf(1.f + __builtin_amdgcn_exp2f(2.88539008f*x));
}

static __device__ __forceinline__ unsigned ldu(const unsigned* p){
  return __hip_atomic_load(p, __ATOMIC_RELAXED, __HIP_MEMORY_SCOPE_AGENT);
}
static __device__ __forceinline__ void stu(unsigned* p, unsigned v){
  __hip_atomic_store(p, v, __ATOMIC_RELAXED, __HIP_MEMORY_SCOPE_AGENT);
}
static __device__ __forceinline__ float ldf(const float* p){
  return __hip_atomic_load(p, __ATOMIC_RELAXED, __HIP_MEMORY_SCOPE_AGENT);
}
static __device__ __forceinline__ void stf(float* p, float v){
  __hip_atomic_store(p, v, __ATOMIC_RELAXED, __HIP_MEMORY_SCOPE_AGENT);
}
static __device__ __forceinline__ void adf(float* p, float v){
  (void)__hip_atomic_fetch_add(p, v, __ATOMIC_RELAXED, __HIP_MEMORY_SCOPE_AGENT);
}
static __device__ __forceinline__ bf16x8 ldh8(const unsigned* p){
  union { unsigned u[4]; bf16x8 v; } x;
  x.u[0] = ldu(p); x.u[1] = ldu(p+1); x.u[2] = ldu(p+2); x.u[3] = ldu(p+3);
  return x.v;
}
#define VMWAIT() __asm__ __volatile__("s_waitcnt vmcnt(0)" ::: "memory")

static __device__ __forceinline__ void slot_barrier(unsigned* myslot, const unsigned* slots,
                                                    int nslots, unsigned target){
  VMWAIT();
  __syncthreads();
  if (threadIdx.x == 0) stu(myslot, target);
  if (threadIdx.x < 64){
    while (true){
      bool ok = true;
      for (int i = (int)threadIdx.x; i < nslots; i += 64)
        ok &= (ldu(&slots[i]) >= target);
      if (__all(ok)) break;
      __builtin_amdgcn_s_sleep(1);
    }
  }
  __syncthreads();
}

// ----------------------------- small utility kernels -----------------------

__global__ void cast_k(const float* __restrict__ src, unsigned short* __restrict__ dst, int n){
  int i = blockIdx.x*256 + threadIdx.x;
  if (i < n) dst[i] = f2bf(src[i]);
}

__global__ void split_attn_k(const float* __restrict__ aw,
                             unsigned short* __restrict__ wh, unsigned short* __restrict__ we){
  int i = blockIdx.x*256 + threadIdx.x;
  int nrow = i >> 9, k = i & 511;
  wh[i] = f2bf(aw[(size_t)nrow*1024 + k]);
  we[i] = f2bf(aw[(size_t)nrow*1024 + 512 + k]);
}

__global__ __launch_bounds__(512) void embed_k(const float* __restrict__ x,
    const float* __restrict__ wconv, unsigned short* __restrict__ out,
    int Bsz, int Lx, int l0, int lcount, int mode){
  __shared__ float wl[512*21];
  __shared__ float xl[66*7];
  int nch = (lcount + 63) / 64;
  int b = blockIdx.x / nch, ci = blockIdx.x % nch;
  int tid = threadIdx.x;
  for (int i = tid; i < 512*21; i += 512) wl[i] = wconv[i];
  int lstart = l0 + ci*64;
  int cnt = l0 + lcount - lstart; if (cnt > 64) cnt = 64;
  int nwin = (cnt + 2) * 7;
  for (int i = tid; i < nwin; i += 512){
    int wr = i / 7, c = i % 7;
    int gl = lstart - 1 + wr;
    gl = (gl + Lx) % Lx;
    xl[i] = x[((size_t)b*Lx + gl)*7 + c];
  }
  __syncthreads();
  int o = tid;
  float fe = (float)(o & ~1);
  float div = __expf(fe * -0.0179889461f);
  const float* wrow = &wl[o*21];
  for (int li = 0; li < cnt; ++li){
    int l = lstart + li;
    float acc = 0.f;
    #pragma unroll
    for (int c = 0; c < 7; ++c)
      #pragma unroll
      for (int kk = 0; kk < 3; ++kk)
        acc += xl[(li + kk)*7 + c] * wrow[c*3 + kk];
    float arg = (float)l * div;
    acc += (o & 1) ? cosf(arg) : sinf(arg);
    size_t oi = mode ? (((size_t)b*lcount + (l - l0))*512 + o)
                     : (((size_t)l*Bsz + b)*512 + o);
    out[oi] = f2bf(acc);
  }
}

// ----------------------------- bf16 NT GEMM --------------------------------
__global__ __launch_bounds__(256) void gemm_nt(const unsigned short* __restrict__ A,
    const unsigned short* __restrict__ Bw, const float* __restrict__ bias,
    unsigned short* __restrict__ C, int M, int N, int K){
  __shared__ __align__(16) unsigned short Asm[128*40];
  __shared__ __align__(16) unsigned short Bsm[128*40];
  const int tid = threadIdx.x;
  const int m0 = blockIdx.y * 128, n0 = blockIdx.x * 128;
  const int lane = tid & 63;
  const int wid = tid >> 6;
  const int wm = (wid >> 1) * 64, wn = (wid & 1) * 64;
  const int fr = lane & 15, q = lane >> 4;
  f32x4 acc[4][4];
  #pragma unroll
  for (int i=0;i<4;i++)
    #pragma unroll
    for(int j=0;j<4;j++) acc[i][j] = (f32x4){0.f,0.f,0.f,0.f};
  for (int k0 = 0; k0 < K; k0 += 32){
    #pragma unroll
    for (int c = 0; c < 2; ++c){
      int ch = tid + c*256;
      int r = ch >> 2, s = (ch & 3) * 8;
      *(uint4*)&Asm[r*40 + s] = *(const uint4*)&A[(size_t)(m0 + r)*K + k0 + s];
      *(uint4*)&Bsm[r*40 + s] = *(const uint4*)&Bw[(size_t)(n0 + r)*K + k0 + s];
    }
    __syncthreads();
    bf16x8 af[4], bfv[4];
    #pragma unroll
    for (int i=0;i<4;i++){
      af[i]  = *(const bf16x8*)&Asm[(wm + i*16 + fr)*40 + q*8];
      bfv[i] = *(const bf16x8*)&Bsm[(wn + i*16 + fr)*40 + q*8];
    }
    #pragma unroll
    for (int i=0;i<4;i++)
      #pragma unroll
      for (int j=0;j<4;j++)
        acc[i][j] = __builtin_amdgcn_mfma_f32_16x16x32_bf16(af[i], bfv[j], acc[i][j], 0,0,0);
    __syncthreads();
  }
  #pragma unroll
  for (int i=0;i<4;i++){
    #pragma unroll
    for (int j=0;j<4;j++){
      int n = n0 + wn + j*16 + fr;
      float bv = bias ? bias[n] : 0.f;
      #pragma unroll
      for (int r=0;r<4;r++){
        int m = m0 + wm + i*16 + q*4 + r;
        C[(size_t)m*N + n] = f2bf(acc[i][j][r] + bv);
      }
    }
  }
}

// ----------------------------- fused encoder + staging GEMM ----------------
#define ENC_SMEM ((64*516 + 16*516)*2 + 16*68*4)
__global__ __launch_bounds__(256) void enc_fused(
    const unsigned short* __restrict__ xw,    // [nsteps][64][2048] bf16
    const unsigned short* __restrict__ whh,   // [2048][512] bf16
    float* __restrict__ cbuf, unsigned* __restrict__ hbuf,
    unsigned short* __restrict__ encout, int t0, int nsteps,
    unsigned* __restrict__ slots,
    const unsigned short* __restrict__ gA, const unsigned short* __restrict__ gB,
    const float* __restrict__ gbias, unsigned short* __restrict__ gC, int gM){
  __shared__ __align__(16) char smem[ENC_SMEM];
  const int tid = threadIdx.x;
  if (blockIdx.x < 128){
    unsigned short* wlds  = (unsigned short*)smem;                 // 64x516
    unsigned short* hblds = wlds + 64*516;                         // 16x516
    float* gbufE = (float*)(smem + (64*516 + 16*516)*2);           // 16x68
    const int g = blockIdx.x >> 5, j = blockIdx.x & 31;
    const int b0 = g*16, u0 = j*16;
    for (int idx = tid; idx < 64*64; idx += 256){
      int n = idx >> 6, ch = idx & 63;
      int R = (n >> 4)*512 + u0 + (n & 15);
      *(uint4*)&wlds[n*516 + ch*8] = *(const uint4*)&whh[(size_t)R*512 + ch*8];
    }
    __syncthreads();
    const int lane = tid & 63, wv = tid >> 6, fr = lane & 15, q = lane >> 4;
    const int m = tid >> 4, j2 = tid & 15;
    float cst = cbuf[(b0 + m)*512 + u0 + j2];
    unsigned* myslot = slots + g*64 + j;
    const unsigned* gslots = slots + g*64;
    unsigned short px0, px1, px2, px3;
    {
      size_t xi = ((size_t)(b0 + m))*2048 + u0 + j2;
      px0 = xw[xi]; px1 = xw[xi + 512]; px2 = xw[xi + 1024]; px3 = xw[xi + 1536];
    }
    for (int s = 0; s < nsteps; ++s){
      const int t = t0 + s;
      const int rp = t & 1, wp = rp ^ 1;
      {
        const unsigned* hbu = hbuf + (size_t)rp*(64*256) + (size_t)b0*256;
        #pragma unroll
        for (int it = 0; it < 16; ++it){
          int idx = it*256 + tid;
          unsigned v = ldu(&hbu[idx]);
          int m2 = idx >> 8, u2 = idx & 255;
          *(unsigned*)&hblds[m2*516 + u2*2] = v;
        }
      }
      __syncthreads();
      f32x4 acc = {0.f,0.f,0.f,0.f};
      #pragma unroll
      for (int k0 = 0; k0 < 512; k0 += 32){
        bf16x8 av = *(const bf16x8*)&hblds[fr*516 + k0 + q*8];
        bf16x8 bv = *(const bf16x8*)&wlds[(wv*16 + fr)*516 + k0 + q*8];
        acc = __builtin_amdgcn_mfma_f32_16x16x32_bf16(av, bv, acc, 0,0,0);
      }
      #pragma unroll
      for (int r = 0; r < 4; ++r)
        gbufE[(q*4 + r)*68 + wv*16 + fr] = acc[r];
      __syncthreads();
      unsigned short hv;
      {
        float gi = gbufE[m*68 + j2]      + bf2f(px0);
        float gf = gbufE[m*68 + 16 + j2] + bf2f(px1);
        float gg = gbufE[m*68 + 32 + j2] + bf2f(px2);
        float go = gbufE[m*68 + 48 + j2] + bf2f(px3);
        float cc = sigm(gf)*cst + sigm(gi)*tanh2(gg);
        float hh = sigm(go)*tanh2(cc);
        cst = cc;
        hv = f2bf(hh);
        unsigned other = (unsigned)__shfl_xor((int)(unsigned)hv, 1);
        if ((j2 & 1) == 0)
          stu(&hbuf[(size_t)wp*(64*256) + (size_t)(b0+m)*256 + ((u0 + j2) >> 1)],
              ((unsigned)hv) | (other << 16));
      }
      // arrive early: publish h, then non-critical work, then wait
      VMWAIT();
      __syncthreads();
      if (tid == 0) stu(myslot, (unsigned)(t + 1));
      encout[((size_t)(b0+m)*512 + t)*512 + u0 + j2] = hv;
      if (s == nsteps - 1) cbuf[(b0+m)*512 + u0 + j2] = cst;
      else {
        size_t xi = ((size_t)(s+1)*64 + b0 + m)*2048 + u0 + j2;
        px0 = xw[xi]; px1 = xw[xi + 512]; px2 = xw[xi + 1024]; px3 = xw[xi + 1536];
      }
      if (tid < 64){
        unsigned target = (unsigned)(t + 1);
        while (true){
          bool ok = true;
          for (int i = (int)tid; i < 32; i += 64)
            ok &= (ldu(&gslots[i]) >= target);
          if (__all(ok)) break;
          __builtin_amdgcn_s_sleep(1);
        }
      }
      __syncthreads();
    }
  } else if (gM > 0){
    unsigned short* Asm = (unsigned short*)smem;      // 128x40
    unsigned short* Bsm = Asm + 128*40;               // 128x40
    int gblk = blockIdx.x - 128;
    const int m0 = (gblk >> 4) * 128, n0 = (gblk & 15) * 128;
    const int lane = tid & 63;
    const int wid = tid >> 6;
    const int wm = (wid >> 1) * 64, wn = (wid & 1) * 64;
    const int fr = lane & 15, q = lane >> 4;
    const int K = 512, N = 2048;
    f32x4 acc[4][4];
    #pragma unroll
    for (int i=0;i<4;i++)
      #pragma unroll
      for(int j=0;j<4;j++) acc[i][j] = (f32x4){0.f,0.f,0.f,0.f};
    for (int k0 = 0; k0 < K; k0 += 32){
      #pragma unroll
      for (int c = 0; c < 2; ++c){
        int ch = tid + c*256;
        int r = ch >> 2, s = (ch & 3) * 8;
        *(uint4*)&Asm[r*40 + s] = *(const uint4*)&gA[(size_t)(m0 + r)*K + k0 + s];
        *(uint4*)&Bsm[r*40 + s] = *(const uint4*)&gB[(size_t)(n0 + r)*K + k0 + s];
      }
      __syncthreads();
      bf16x8 af[4], bfv[4];
      #pragma unroll
      for (int i=0;i<4;i++){
        af[i]  = *(const bf16x8*)&Asm[(wm + i*16 + fr)*40 + q*8];
        bfv[i] = *(const bf16x8*)&Bsm[(wn + i*16 + fr)*40 + q*8];
      }
      #pragma unroll
      for (int i=0;i<4;i++)
        #pragma unroll
        for (int j=0;j<4;j++)
          acc[i][j] = __builtin_amdgcn_mfma_f32_16x16x32_bf16(af[i], bfv[j], acc[i][j], 0,0,0);
      __syncthreads();
    }
    #pragma unroll
    for (int i=0;i<4;i++){
      #pragma unroll
      for (int j=0;j<4;j++){
        int n = n0 + wn + j*16 + fr;
        float bv = gbias[n];
        #pragma unroll
        for (int r=0;r<4;r++){
          int mm = m0 + wm + i*16 + q*4 + r;
          gC[(size_t)mm*N + n] = f2bf(acc[i][j][r] + bv);
        }
      }
    }
  }
}

// ----------------------------- decoder -------------------------------------
// 256 blocks x 512 thr, 48 steps, 2 full barriers/step + one-way hwh handoff.
// Phase A: blocks 0-127 (P): gates -> h_t.  (Q idle.)
// Phase C: P: hwh rows (from h_t!) -> publish hwslot; Q: fc(t-1) meanwhile;
//          all: poll hwslot, then scores + stale-shift softmax + ctx.
__global__ __launch_bounds__(512) void lstm_dec(
    const unsigned short* __restrict__ xg,      // [64][48][2048] bf16 (bias folded)
    const unsigned short* __restrict__ whh,     // dec_Whh bf16 [2048][512]
    const unsigned short* __restrict__ whq,     // Wh bf16 [512][512]
    const unsigned short* __restrict__ fcw,     // fc_W bf16 [512][1024]
    const float* __restrict__ fcb, const float* __restrict__ vvec,
    const unsigned short* __restrict__ encpart, // [64*512][512] bf16
    const unsigned short* __restrict__ encout,  // [64*512][512] bf16
    unsigned* __restrict__ hbuf,                // [2][64][256] dwords
    const float* __restrict__ cbuf,
    float* __restrict__ hwhg,                   // [64][512] f32
    float* __restrict__ ctx48,                  // [48][64][512] zeroed
    float* __restrict__ Zbuf,                   // [48][64] zeroed
    float* __restrict__ smaxb,                  // [49][64][4]; row0 zeroed
    unsigned short* __restrict__ outs,
    unsigned* __restrict__ slots, unsigned* __restrict__ hwslot){
  __shared__ __align__(16) unsigned short wlds[16*516];
  __shared__ __align__(16) unsigned short whlds[16*516];
  __shared__ __align__(16) unsigned short fcwlds[4*1032];
  __shared__ __align__(16) unsigned short hstage[64*516];
  __shared__ float gbuf[64*17];
  __shared__ __align__(16) float hwhs[512];
  __shared__ __align__(16) float vm2[512];
  __shared__ float sc[128];
  __shared__ float aw[128];
  __shared__ float ctxlds[1024];
  __shared__ float zinv[64];
  __shared__ float red[16];
  __shared__ float mpv;
  const int tid = threadIdx.x, blk = blockIdx.x;
  const int lane = tid & 63, wv = tid >> 6, fr = lane & 15, q = lane >> 4;
  const int ab = blk >> 2, ls = blk & 3;
  const bool isP = blk < 128;
  if (isP){
    for (int idx = tid; idx < 16*64; idx += 512){
      int n = idx >> 6, ch = idx & 63;
      int R = (n >> 2)*512 + blk*4 + (n & 3);   // [i(4), f(4), g(4), o(4)]
      *(uint4*)&wlds[n*516 + ch*8] = *(const uint4*)&whh[(size_t)R*512 + ch*8];
    }
    for (int idx = tid; idx < 4*64; idx += 512){
      int n = idx >> 6, ch = idx & 63;
      *(uint4*)&whlds[n*516 + ch*8] = *(const uint4*)&whq[((size_t)(blk*4 + n))*512 + ch*8];
    }
    for (int idx = tid; idx < 12*64; idx += 512){
      int n = 4 + (idx >> 6), ch = idx & 63;
      *(uint4*)&whlds[n*516 + ch*8] = (uint4){0u,0u,0u,0u};
    }
  } else {
    int fb = blk - 128;
    for (int idx = tid; idx < 4*128; idx += 512){
      int r = idx >> 7, ch = idx & 127;
      *(uint4*)&fcwlds[r*1032 + ch*8] = *(const uint4*)&fcw[((size_t)(fb*4 + r))*1024 + ch*8];
    }
  }
  vm2[tid] = -2.f * vvec[tid];
  __syncthreads();
  float vsumf;
  {
    float x = vm2[tid];
    #pragma unroll
    for (int off=32; off; off>>=1) x += __shfl_xor(x, off);
    if (lane == 0) red[wv] = x;
    __syncthreads();
    float s = 0.f;
    #pragma unroll
    for (int i=0;i<8;i++) s += red[i];
    vsumf = -0.5f * s;
    __syncthreads();
  }
  const int um = tid >> 2, uj = tid & 3;
  float cst = (isP && tid < 256) ? cbuf[um*512 + blk*4 + uj] : 0.f;
  unsigned* myslot = slots + blk;

  auto do_fc = [&](int tt){
    int fb = blk - 128;
    int b = tid >> 3, q8 = tid & 7;
    if (tid < 64) zinv[tid] = __builtin_amdgcn_rcpf(ldf(&Zbuf[tt*64 + tid]));
    __syncthreads();
    float s4[4] = {0.f,0.f,0.f,0.f};
    if (q8 < 4){
      int hp = (tt + 1) & 1;
      const unsigned* hb = hbuf + (size_t)hp*(64*256) + (size_t)b*256 + q8*64;
      for (int c = 0; c < 16; ++c){
        bf16x8 h8 = ldh8(&hb[c*4]);
        float hf[8];
        #pragma unroll
        for (int e=0;e<8;e++) hf[e] = bf2f(((const unsigned short*)&h8)[e]);
        #pragma unroll
        for (int r = 0; r < 4; ++r){
          bf16x8 w8 = *(const bf16x8*)&fcwlds[r*1032 + q8*128 + c*8];
          #pragma unroll
          for (int e = 0; e < 8; ++e)
            s4[r] += hf[e] * bf2f(((const unsigned short*)&w8)[e]);
        }
      }
    } else {
      int hh = (q8 - 4)*128;
      const float* cp = &ctx48[((size_t)tt*64 + b)*512 + hh];
      float iz = zinv[b];
      for (int c = 0; c < 16; ++c){
        float cf[8];
        #pragma unroll
        for (int e = 0; e < 8; ++e) cf[e] = ldf(&cp[c*8 + e]) * iz;
        #pragma unroll
        for (int r = 0; r < 4; ++r){
          bf16x8 w8 = *(const bf16x8*)&fcwlds[r*1032 + 512 + hh + c*8];
          #pragma unroll
          for (int e = 0; e < 8; ++e)
            s4[r] += cf[e] * bf2f(((const unsigned short*)&w8)[e]);
        }
      }
    }
    #pragma unroll
    for (int r = 0; r < 4; ++r){
      s4[r] += __shfl_xor(s4[r], 1);
      s4[r] += __shfl_xor(s4[r], 2);
      s4[r] += __shfl_xor(s4[r], 4);
    }
    if (q8 == 0){
      #pragma unroll
      for (int r = 0; r < 4; ++r)
        outs[((size_t)b*48 + tt)*512 + fb*4 + r] = f2bf(s4[r] + fcb[fb*4 + r]);
    }
  };

  for (int t = 0; t < 48; ++t){
    const int rp = t & 1, wp = rp ^ 1;
    // ---- phase A: gates (P blocks only)
    if (isP){
      const unsigned* hb = hbuf + (size_t)rp*(64*256);
      #pragma unroll
      for (int it = 0; it < 32; ++it){
        int idx = it*512 + tid;
        unsigned v = ldu(&hb[idx]);
        int m2 = idx >> 8, u2 = idx & 255;
        *(unsigned*)&hstage[m2*516 + u2*2] = v;
      }
      __syncthreads();
      if (wv < 4){
        f32x4 a0 = {0.f,0.f,0.f,0.f};
        #pragma unroll
        for (int k0 = 0; k0 < 512; k0 += 32){
          bf16x8 av = *(const bf16x8*)&hstage[(wv*16 + fr)*516 + k0 + q*8];
          bf16x8 bv = *(const bf16x8*)&wlds[fr*516 + k0 + q*8];
          a0 = __builtin_amdgcn_mfma_f32_16x16x32_bf16(av, bv, a0, 0,0,0);
        }
        #pragma unroll
        for (int r = 0; r < 4; ++r) gbuf[(wv*16 + q*4 + r)*17 + fr] = a0[r];
      }
      __syncthreads();
      if (tid < 256){
        size_t xi = ((size_t)um*48 + t)*2048 + blk*4 + uj;
        float gi = gbuf[um*17 + uj]       + bf2f(xg[xi]);
        float gf = gbuf[um*17 + 4 + uj]   + bf2f(xg[xi + 512]);
        float gg = gbuf[um*17 + 8 + uj]   + bf2f(xg[xi + 1024]);
        float go = gbuf[um*17 + 12 + uj]  + bf2f(xg[xi + 1536]);
        float cc = sigm(gf)*cst + sigm(gi)*tanh2(gg);
        float hh = sigm(go)*tanh2(cc);
        cst = cc;
        unsigned short hv = f2bf(hh);
        unsigned other = (unsigned)__shfl_xor((int)(unsigned)hv, 1);
        if ((uj & 1) == 0)
          stu(&hbuf[(size_t)wp*(64*256) + (size_t)um*256 + ((blk*4 + uj) >> 1)],
              ((unsigned)hv) | (other << 16));
      }
    }
    slot_barrier(myslot, slots, 256, 2u*t + 1);
    // ---- phase C part 1: hwh from h_t (P) | fc(t-1) (Q)
    if (isP){
      if (wv < 4){
        const unsigned* hb2 = hbuf + (size_t)wp*(64*256);
        f32x4 a1 = {0.f,0.f,0.f,0.f};
        #pragma unroll
        for (int k0 = 0; k0 < 512; k0 += 32){
          bf16x8 av = ldh8(&hb2[(size_t)(wv*16 + fr)*256 + (k0 >> 1) + q*4]);
          bf16x8 bv = *(const bf16x8*)&whlds[fr*516 + k0 + q*8];
          a1 = __builtin_amdgcn_mfma_f32_16x16x32_bf16(av, bv, a1, 0,0,0);
        }
        if (fr < 4){
          int k = blk*4 + fr;
          #pragma unroll
          for (int r = 0; r < 4; ++r)
            stf(&hwhg[(size_t)(wv*16 + q*4 + r)*512 + k], a1[r]);
        }
      }
      VMWAIT();
      __syncthreads();
      if (tid == 0) stu(&hwslot[blk], (unsigned)(t + 1));
    } else if (t > 0){
      do_fc(t - 1);
    }
    // one-way wait: hwh producers done?
    if (tid < 64){
      unsigned target = (unsigned)(t + 1);
      while (true){
        bool ok = true;
        #pragma unroll
        for (int i = 0; i < 2; ++i)
          ok &= (ldu(&hwslot[tid + i*64]) >= target);
        if (__all(ok)) break;
        __builtin_amdgcn_s_sleep(1);
      }
    }
    __syncthreads();
    // ---- phase C part 2: scores + stale-shift softmax + ctx partials
    {
      hwhs[tid] = 2.88539008f * ldf(&hwhg[ab*512 + tid]);
      if (tid == 0){
        const float* sm = &smaxb[((size_t)t*64 + ab)*4];
        mpv = fmaxf(fmaxf(ldf(&sm[0]), ldf(&sm[1])), fmaxf(ldf(&sm[2]), ldf(&sm[3])));
      }
      __syncthreads();
      const float mp = mpv;
      const int row = tid >> 2, q4 = tid & 3;
      const unsigned short* ep = encpart + ((size_t)(ab*512 + ls*128 + row))*512 + q4*128;
      float sacc = 0.f;
      for (int kk = 0; kk < 128; kk += 8){
        bf16x8 e8 = *(const bf16x8*)&ep[kk];
        #pragma unroll
        for (int e = 0; e < 8; ++e){
          int ki = q4*128 + kk + e;
          float a = fmaf(bf2f(((const unsigned short*)&e8)[e]), 2.88539008f, hwhs[ki]);
          sacc += vm2[ki] * __builtin_amdgcn_rcpf(1.f + __builtin_amdgcn_exp2f(a));
        }
      }
      sacc += __shfl_xor(sacc, 1);
      sacc += __shfl_xor(sacc, 2);
      if (q4 == 0) sc[row] = vsumf + sacc;
      __syncthreads();
      float x = (tid < 128) ? sc[tid] : -3.0e38f;
      float w = (tid < 128) ? __builtin_amdgcn_exp2f(1.44269504f*(x - mp)) : 0.f;
      if (tid < 128) aw[tid] = w;
      #pragma unroll
      for (int off=32; off; off>>=1){
        x = fmaxf(x, __shfl_xor(x, off));
        w += __shfl_xor(w, off);
      }
      if (lane == 0){ red[wv] = x; red[8 + wv] = w; }
      __syncthreads();
      if (tid == 0){
        float mx = fmaxf(red[0], red[1]);
        float Zs = red[8] + red[9];
        adf(&Zbuf[t*64 + ab], Zs);
        stf(&smaxb[((size_t)(t+1)*64 + ab)*4 + ls], mx);
      }
      const int hp2 = tid & 255, half = tid >> 8;
      const unsigned short* eo = encout + ((size_t)(ab*512 + ls*128 + half*64))*512 + 2*hp2;
      float ax = 0.f, ay = 0.f;
      #pragma unroll 4
      for (int il = 0; il < 64; ++il){
        float aww = aw[half*64 + il];
        unsigned ee = *(const unsigned*)(eo + (size_t)il*512);
        ax += aww * __uint_as_float((ee & 0xffffu) << 16);
        ay += aww * __uint_as_float(ee & 0xffff0000u);
      }
      ctxlds[half*512 + 2*hp2]     = ax;
      ctxlds[half*512 + 2*hp2 + 1] = ay;
      __syncthreads();
      if (tid < 256){
        float c0 = ctxlds[2*tid]     + ctxlds[512 + 2*tid];
        float c1 = ctxlds[2*tid + 1] + ctxlds[512 + 2*tid + 1];
        float* cb = &ctx48[((size_t)t*64 + ab)*512];
        adf(&cb[2*tid], c0);
        adf(&cb[2*tid + 1], c1);
      }
    }
    slot_barrier(myslot, slots, 256, 2u*t + 2);
  }
  if (!isP) do_fc(47);
}

// ----------------------------- projection ----------------------------------
__global__ void proj_k(const unsigned short* __restrict__ outs,
                       const float* __restrict__ pw, const float* __restrict__ pb,
                       float* __restrict__ out){
  int gid = blockIdx.x*256 + threadIdx.x;
  if (gid >= 64*48*7) return;
  int row = gid / 7, oc = gid % 7;
  const unsigned short* orow = outs + (size_t)row*512;
  const float* wrow = pw + oc*512;
  float s = pb[oc];
  for (int k = 0; k < 512; k += 8){
    bf16x8 o8 = *(const bf16x8*)&orow[k];
    #pragma unroll
    for (int e=0;e<8;e++) s += bf2f(((unsigned short*)&o8)[e]) * wrow[k+e];
  }
  out[gid] = s;
}

// ----------------------------- launch --------------------------------------
extern "C" void kernel_launch(void* const* d_in, const int* in_sizes, int n_in,
                              void* d_out, int out_size, void* d_ws, size_t ws_size,
                              hipStream_t stream){
  (void)in_sizes; (void)n_in; (void)out_size; (void)ws_size;
  const float* x_enc   = (const float*)d_in[0];
  const float* x_dec   = (const float*)d_in[1];
  const float* w_emb_e = (const float*)d_in[2];
  const float* w_emb_d = (const float*)d_in[3];
  const float* enc_Wih = (const float*)d_in[4];
  const float* enc_Whh = (const float*)d_in[5];
  const float* enc_b   = (const float*)d_in[6];
  const float* dec_Wih = (const float*)d_in[7];
  const float* dec_Whh = (const float*)d_in[8];
  const float* dec_b   = (const float*)d_in[9];
  const float* attn_W  = (const float*)d_in[10];
  const float* attn_b  = (const float*)d_in[11];
  const float* vvec    = (const float*)d_in[12];
  const float* fc_W    = (const float*)d_in[13];
  const float* fc_b    = (const float*)d_in[14];
  const float* proj_W  = (const float*)d_in[15];
  const float* proj_b  = (const float*)d_in[16];
  float* out = (float*)d_out;

  char* ws = (char*)d_ws;
  size_t off = 0;
  auto alloc = [&](size_t bytes)->char*{
    char* p = ws + off;
    off = (off + bytes + 255) & ~(size_t)255;
    return p;
  };
  unsigned short* encxw0 = (unsigned short*)alloc(128ull*64*2048*2);
  unsigned short* encxw1 = (unsigned short*)alloc(128ull*64*2048*2);
  unsigned short* encin  = (unsigned short*)alloc(512ull*64*512*2);  // embed; reused as enc_part
  unsigned short* encout = (unsigned short*)alloc(64ull*512*512*2);
  unsigned short* xs     = (unsigned short*)alloc(64ull*48*512*2);
  unsigned short* xg     = (unsigned short*)alloc(64ull*48*2048*2);
  unsigned short* outsb  = (unsigned short*)alloc(64ull*48*512*2);
  unsigned short* wih_e  = (unsigned short*)alloc(2048ull*512*2);
  unsigned short* whh_e  = (unsigned short*)alloc(2048ull*512*2);
  unsigned short* wih_d  = (unsigned short*)alloc(2048ull*512*2);
  unsigned short* whh_d  = (unsigned short*)alloc(2048ull*512*2);
  unsigned short* whq    = (unsigned short*)alloc(512ull*512*2);
  unsigned short* weq    = (unsigned short*)alloc(512ull*512*2);
  unsigned short* fcw    = (unsigned short*)alloc(512ull*1024*2);
  unsigned* hbuf  = (unsigned*)alloc(2ull*64*256*4);
  float* cbuf   = (float*)alloc(64ull*512*4);
  float* hwhg   = (float*)alloc(64ull*512*4);
  float* ctx48  = (float*)alloc(48ull*64*512*4);
  float* Zbuf   = (float*)alloc(48ull*64*4);
  float* smaxb  = (float*)alloc(49ull*64*4*4);
  unsigned* eslots = (unsigned*)alloc(4*64*4);
  unsigned* dslots = (unsigned*)alloc(256*4);
  unsigned* hwslot = (unsigned*)alloc(128*4);

  hipMemsetAsync(eslots, 0, 4*64*4, stream);
  hipMemsetAsync(dslots, 0, 256*4, stream);
  hipMemsetAsync(hwslot, 0, 128*4, stream);
  hipMemsetAsync(hbuf, 0, 2ull*64*256*4, stream);
  hipMemsetAsync(cbuf, 0, 64ull*512*4, stream);
  hipMemsetAsync(ctx48, 0, 48ull*64*512*4, stream);
  hipMemsetAsync(Zbuf, 0, 48ull*64*4, stream);
  hipMemsetAsync(smaxb, 0, 49ull*64*4*4, stream);

  cast_k<<<4096, 256, 0, stream>>>(enc_Wih, wih_e, 2048*512);
  cast_k<<<4096, 256, 0, stream>>>(enc_Whh, whh_e, 2048*512);
  cast_k<<<4096, 256, 0, stream>>>(dec_Wih, wih_d, 2048*512);
  cast_k<<<4096, 256, 0, stream>>>(dec_Whh, whh_d, 2048*512);
  cast_k<<<2048, 256, 0, stream>>>(fc_W, fcw, 512*1024);
  split_attn_k<<<1024, 256, 0, stream>>>(attn_W, whq, weq);

  embed_k<<<512, 512, 0, stream>>>(x_enc, w_emb_e, encin, 64, 512, 0, 512, 0);
  embed_k<<<64, 512, 0, stream>>>(x_dec, w_emb_d, xs, 64, 144, 48, 48, 1);

  gemm_nt<<<dim3(16, 24), 256, 0, stream>>>(xs, wih_d, dec_b, xg, 3072, 2048, 512);

  gemm_nt<<<dim3(16, 64), 256, 0, stream>>>(encin, wih_e, enc_b, encxw0, 8192, 2048, 512);
  enc_fused<<<1152, 256, 0, stream>>>(encxw0, whh_e, cbuf, hbuf, encout, 0, 128, eslots,
                                      encin + (size_t)1*8192*512, wih_e, enc_b, encxw1, 8192);
  enc_fused<<<1152, 256, 0, stream>>>(encxw1, whh_e, cbuf, hbuf, encout, 128, 128, eslots,
                                      encin + (size_t)2*8192*512, wih_e, enc_b, encxw0, 8192);
  enc_fused<<<1152, 256, 0, stream>>>(encxw0, whh_e, cbuf, hbuf, encout, 256, 128, eslots,
                                      encin + (size_t)3*8192*512, wih_e, enc_b, encxw1, 8192);
  enc_fused<<<128, 256, 0, stream>>>(encxw1, whh_e, cbuf, hbuf, encout, 384, 128, eslots,
                                     (const unsigned short*)0, (const unsigned short*)0,
                                     (const float*)0, (unsigned short*)0, 0);

  gemm_nt<<<dim3(4, 256), 256, 0, stream>>>(encout, weq, attn_b, encin /*enc_part*/, 32768, 512, 512);

  lstm_dec<<<256, 512, 0, stream>>>(xg, whh_d, whq, fcw, fc_b, vvec,
                                    encin /*enc_part*/, encout, hbuf, cbuf,
                                    hwhg, ctx48, Zbuf, smaxb, outsb, dslots, hwslot);

  proj_k<<<84, 256, 0, stream>>>(outsb, proj_W, proj_b, out);
}

// Round 7
// 4016.867 us; speedup vs baseline: 2.0488x; 2.0488x over previous
//
#include <hip/hip_runtime.h>
#include <hip/hip_bf16.h>

// ---------------------------------------------------------------------------
// conv1d embed -> LSTM encoder (512 steps, B=64, H=512) -> decoder.
// DECODER DECOUPLING: the attention/fc path never feeds the LSTM recurrence
// (scan carry is only (h,c)), so: (1) run the 48-step decoder LSTM alone
// (persistent kernel, enc-style), then (2) run ALL attention for all 48 steps
// as parallel batched kernels: hWh GEMM -> scores (ep in registers, 48 t per
// block) -> rowwise softmax -> ctx weighted-sum -> fc GEMM -> proj.
// r7: fix ctx_k weight unpack (elements 10,11 duplicated 8,9 in r6).
// ---------------------------------------------------------------------------

typedef short bf16x8 __attribute__((ext_vector_type(8)));
typedef float f32x4 __attribute__((ext_vector_type(4)));

static __device__ __forceinline__ float bf2f(unsigned short u){
  return __uint_as_float(((unsigned)u) << 16);
}
static __device__ __forceinline__ unsigned short f2bf(float f){
  unsigned x = __float_as_uint(f);
  return (unsigned short)((x + 0x7fffu + ((x >> 16) & 1u)) >> 16);   // RNE
}
static __device__ __forceinline__ float sigm(float x){
  return __builtin_amdgcn_rcpf(1.f + __builtin_amdgcn_exp2f(-1.44269504f*x));
}
static __device__ __forceinline__ float tanh2(float x){
  return 1.f - 2.f*__builtin_amdgcn_rcpf(1.f + __builtin_amdgcn_exp2f(2.88539008f*x));
}

static __device__ __forceinline__ unsigned ldu(const unsigned* p){
  return __hip_atomic_load(p, __ATOMIC_RELAXED, __HIP_MEMORY_SCOPE_AGENT);
}
static __device__ __forceinline__ void stu(unsigned* p, unsigned v){
  __hip_atomic_store(p, v, __ATOMIC_RELAXED, __HIP_MEMORY_SCOPE_AGENT);
}
#define VMWAIT() __asm__ __volatile__("s_waitcnt vmcnt(0)" ::: "memory")

// ----------------------------- small utility kernels -----------------------

__global__ void cast_k(const float* __restrict__ src, unsigned short* __restrict__ dst, int n){
  int i = blockIdx.x*256 + threadIdx.x;
  if (i < n) dst[i] = f2bf(src[i]);
}

__global__ void split_attn_k(const float* __restrict__ aw,
                             unsigned short* __restrict__ wh, unsigned short* __restrict__ we){
  int i = blockIdx.x*256 + threadIdx.x;
  int nrow = i >> 9, k = i & 511;
  wh[i] = f2bf(aw[(size_t)nrow*1024 + k]);
  we[i] = f2bf(aw[(size_t)nrow*1024 + 512 + k]);
}

__global__ __launch_bounds__(512) void embed_k(const float* __restrict__ x,
    const float* __restrict__ wconv, unsigned short* __restrict__ out,
    int Bsz, int Lx, int l0, int lcount, int mode){
  __shared__ float wl[512*21];
  __shared__ float xl[66*7];
  int nch = (lcount + 63) / 64;
  int b = blockIdx.x / nch, ci = blockIdx.x % nch;
  int tid = threadIdx.x;
  for (int i = tid; i < 512*21; i += 512) wl[i] = wconv[i];
  int lstart = l0 + ci*64;
  int cnt = l0 + lcount - lstart; if (cnt > 64) cnt = 64;
  int nwin = (cnt + 2) * 7;
  for (int i = tid; i < nwin; i += 512){
    int wr = i / 7, c = i % 7;
    int gl = lstart - 1 + wr;
    gl = (gl + Lx) % Lx;
    xl[i] = x[((size_t)b*Lx + gl)*7 + c];
  }
  __syncthreads();
  int o = tid;
  float fe = (float)(o & ~1);
  float div = __expf(fe * -0.0179889461f);
  const float* wrow = &wl[o*21];
  for (int li = 0; li < cnt; ++li){
    int l = lstart + li;
    float acc = 0.f;
    #pragma unroll
    for (int c = 0; c < 7; ++c)
      #pragma unroll
      for (int kk = 0; kk < 3; ++kk)
        acc += xl[(li + kk)*7 + c] * wrow[c*3 + kk];
    float arg = (float)l * div;
    acc += (o & 1) ? cosf(arg) : sinf(arg);
    size_t oi = mode ? (((size_t)b*lcount + (l - l0))*512 + o)
                     : (((size_t)l*Bsz + b)*512 + o);
    out[oi] = f2bf(acc);
  }
}

// ----------------------------- bf16 NT GEMM (lda/ldb/ldc) ------------------
__global__ __launch_bounds__(256) void gemm_nt(const unsigned short* __restrict__ A, int lda,
    const unsigned short* __restrict__ Bw, int ldb, const float* __restrict__ bias,
    unsigned short* __restrict__ C, int ldc, int M, int N, int K){
  __shared__ __align__(16) unsigned short Asm[128*40];
  __shared__ __align__(16) unsigned short Bsm[128*40];
  const int tid = threadIdx.x;
  const int m0 = blockIdx.y * 128, n0 = blockIdx.x * 128;
  const int lane = tid & 63;
  const int wid = tid >> 6;
  const int wm = (wid >> 1) * 64, wn = (wid & 1) * 64;
  const int fr = lane & 15, q = lane >> 4;
  f32x4 acc[4][4];
  #pragma unroll
  for (int i=0;i<4;i++)
    #pragma unroll
    for(int j=0;j<4;j++) acc[i][j] = (f32x4){0.f,0.f,0.f,0.f};
  for (int k0 = 0; k0 < K; k0 += 32){
    #pragma unroll
    for (int c = 0; c < 2; ++c){
      int ch = tid + c*256;
      int r = ch >> 2, s = (ch & 3) * 8;
      *(uint4*)&Asm[r*40 + s] = *(const uint4*)&A[(size_t)(m0 + r)*lda + k0 + s];
      *(uint4*)&Bsm[r*40 + s] = *(const uint4*)&Bw[(size_t)(n0 + r)*ldb + k0 + s];
    }
    __syncthreads();
    bf16x8 af[4], bfv[4];
    #pragma unroll
    for (int i=0;i<4;i++){
      af[i]  = *(const bf16x8*)&Asm[(wm + i*16 + fr)*40 + q*8];
      bfv[i] = *(const bf16x8*)&Bsm[(wn + i*16 + fr)*40 + q*8];
    }
    #pragma unroll
    for (int i=0;i<4;i++)
      #pragma unroll
      for (int j=0;j<4;j++)
        acc[i][j] = __builtin_amdgcn_mfma_f32_16x16x32_bf16(af[i], bfv[j], acc[i][j], 0,0,0);
    __syncthreads();
  }
  #pragma unroll
  for (int i=0;i<4;i++){
    #pragma unroll
    for (int j=0;j<4;j++){
      int n = n0 + wn + j*16 + fr;
      float bv = bias ? bias[n] : 0.f;
      #pragma unroll
      for (int r=0;r<4;r++){
        int m = m0 + wm + i*16 + q*4 + r;
        C[(size_t)m*ldc + n] = f2bf(acc[i][j][r] + bv);
      }
    }
  }
}

// f32-output variant (for hWh)
__global__ __launch_bounds__(256) void gemm_ntf(const unsigned short* __restrict__ A, int lda,
    const unsigned short* __restrict__ Bw, int ldb,
    float* __restrict__ C, int ldc, int M, int N, int K){
  __shared__ __align__(16) unsigned short Asm[128*40];
  __shared__ __align__(16) unsigned short Bsm[128*40];
  const int tid = threadIdx.x;
  const int m0 = blockIdx.y * 128, n0 = blockIdx.x * 128;
  const int lane = tid & 63;
  const int wid = tid >> 6;
  const int wm = (wid >> 1) * 64, wn = (wid & 1) * 64;
  const int fr = lane & 15, q = lane >> 4;
  f32x4 acc[4][4];
  #pragma unroll
  for (int i=0;i<4;i++)
    #pragma unroll
    for(int j=0;j<4;j++) acc[i][j] = (f32x4){0.f,0.f,0.f,0.f};
  for (int k0 = 0; k0 < K; k0 += 32){
    #pragma unroll
    for (int c = 0; c < 2; ++c){
      int ch = tid + c*256;
      int r = ch >> 2, s = (ch & 3) * 8;
      *(uint4*)&Asm[r*40 + s] = *(const uint4*)&A[(size_t)(m0 + r)*lda + k0 + s];
      *(uint4*)&Bsm[r*40 + s] = *(const uint4*)&Bw[(size_t)(n0 + r)*ldb + k0 + s];
    }
    __syncthreads();
    bf16x8 af[4], bfv[4];
    #pragma unroll
    for (int i=0;i<4;i++){
      af[i]  = *(const bf16x8*)&Asm[(wm + i*16 + fr)*40 + q*8];
      bfv[i] = *(const bf16x8*)&Bsm[(wn + i*16 + fr)*40 + q*8];
    }
    #pragma unroll
    for (int i=0;i<4;i++)
      #pragma unroll
      for (int j=0;j<4;j++)
        acc[i][j] = __builtin_amdgcn_mfma_f32_16x16x32_bf16(af[i], bfv[j], acc[i][j], 0,0,0);
    __syncthreads();
  }
  #pragma unroll
  for (int i=0;i<4;i++){
    #pragma unroll
    for (int j=0;j<4;j++){
      int n = n0 + wn + j*16 + fr;
      #pragma unroll
      for (int r=0;r<4;r++){
        int m = m0 + wm + i*16 + q*4 + r;
        C[(size_t)m*ldc + n] = acc[i][j][r];
      }
    }
  }
}

// ----------------------------- encoder LSTM --------------------------------
// 128 blocks = 4 batch-groups (16 b) x 32 unit-blocks (16 u). Fence-free
// slot barrier per group; h via relaxed agent atomics; arrive-early.
__global__ __launch_bounds__(256) void lstm_enc(
    const unsigned short* __restrict__ xw,    // [nsteps][64][2048] bf16 (bias folded)
    const unsigned short* __restrict__ whh,   // [2048][512] bf16
    float* __restrict__ cbuf, unsigned* __restrict__ hbuf,
    unsigned short* __restrict__ encout,      // [64][512][512]
    int t0, int nsteps, unsigned* __restrict__ slots){
  __shared__ __align__(16) unsigned short wlds[64*516];
  __shared__ __align__(16) unsigned short hblds[16*516];
  __shared__ float gbufE[16*68];
  const int tid = threadIdx.x;
  const int g = blockIdx.x >> 5, j = blockIdx.x & 31;
  const int b0 = g*16, u0 = j*16;
  for (int idx = tid; idx < 64*64; idx += 256){
    int n = idx >> 6, ch = idx & 63;
    int R = (n >> 4)*512 + u0 + (n & 15);
    *(uint4*)&wlds[n*516 + ch*8] = *(const uint4*)&whh[(size_t)R*512 + ch*8];
  }
  __syncthreads();
  const int lane = tid & 63, wv = tid >> 6, fr = lane & 15, q = lane >> 4;
  const int m = tid >> 4, j2 = tid & 15;
  float cst = cbuf[(b0 + m)*512 + u0 + j2];
  unsigned* myslot = slots + g*64 + j;
  const unsigned* gslots = slots + g*64;
  unsigned short px0, px1, px2, px3;
  {
    size_t xi = ((size_t)(b0 + m))*2048 + u0 + j2;
    px0 = xw[xi]; px1 = xw[xi + 512]; px2 = xw[xi + 1024]; px3 = xw[xi + 1536];
  }
  for (int s = 0; s < nsteps; ++s){
    const int t = t0 + s;
    const int rp = t & 1, wp = rp ^ 1;
    {
      const unsigned* hbu = hbuf + (size_t)rp*(64*256) + (size_t)b0*256;
      #pragma unroll
      for (int it = 0; it < 16; ++it){
        int idx = it*256 + tid;
        unsigned v = ldu(&hbu[idx]);
        int m2 = idx >> 8, u2 = idx & 255;
        *(unsigned*)&hblds[m2*516 + u2*2] = v;
      }
    }
    __syncthreads();
    f32x4 acc = {0.f,0.f,0.f,0.f};
    #pragma unroll
    for (int k0 = 0; k0 < 512; k0 += 32){
      bf16x8 av = *(const bf16x8*)&hblds[fr*516 + k0 + q*8];
      bf16x8 bv = *(const bf16x8*)&wlds[(wv*16 + fr)*516 + k0 + q*8];
      acc = __builtin_amdgcn_mfma_f32_16x16x32_bf16(av, bv, acc, 0,0,0);
    }
    #pragma unroll
    for (int r = 0; r < 4; ++r)
      gbufE[(q*4 + r)*68 + wv*16 + fr] = acc[r];
    __syncthreads();
    unsigned short hv;
    {
      float gi = gbufE[m*68 + j2]      + bf2f(px0);
      float gf = gbufE[m*68 + 16 + j2] + bf2f(px1);
      float gg = gbufE[m*68 + 32 + j2] + bf2f(px2);
      float go = gbufE[m*68 + 48 + j2] + bf2f(px3);
      float cc = sigm(gf)*cst + sigm(gi)*tanh2(gg);
      float hh = sigm(go)*tanh2(cc);
      cst = cc;
      hv = f2bf(hh);
      unsigned other = (unsigned)__shfl_xor((int)(unsigned)hv, 1);
      if ((j2 & 1) == 0)
        stu(&hbuf[(size_t)wp*(64*256) + (size_t)(b0+m)*256 + ((u0 + j2) >> 1)],
            ((unsigned)hv) | (other << 16));
    }
    VMWAIT();
    __syncthreads();
    if (tid == 0) stu(myslot, (unsigned)(t + 1));
    encout[((size_t)(b0+m)*512 + t)*512 + u0 + j2] = hv;
    if (s == nsteps - 1) cbuf[(b0+m)*512 + u0 + j2] = cst;
    else {
      size_t xi = ((size_t)(s+1)*64 + b0 + m)*2048 + u0 + j2;
      px0 = xw[xi]; px1 = xw[xi + 512]; px2 = xw[xi + 1024]; px3 = xw[xi + 1536];
    }
    if (tid < 64){
      unsigned target = (unsigned)(t + 1);
      while (true){
        bool ok = true;
        for (int i = (int)tid; i < 32; i += 64)
          ok &= (ldu(&gslots[i]) >= target);
        if (__all(ok)) break;
        __builtin_amdgcn_s_sleep(1);
      }
    }
    __syncthreads();
  }
}

// ----------------------------- decoder LSTM (h-sequence only) --------------
__global__ __launch_bounds__(256) void dec_h(
    const unsigned short* __restrict__ xg,    // [64][48][2048] bf16 (bias folded)
    const unsigned short* __restrict__ whh,   // dec_Whh [2048][512] bf16
    const float* __restrict__ cbuf, unsigned* __restrict__ hbuf,
    unsigned short* __restrict__ X,           // [3072][1024]
    unsigned* __restrict__ slots){
  __shared__ __align__(16) unsigned short wlds[64*516];
  __shared__ __align__(16) unsigned short hblds[16*516];
  __shared__ float gbufE[16*68];
  const int tid = threadIdx.x;
  const int g = blockIdx.x >> 5, j = blockIdx.x & 31;
  const int b0 = g*16, u0 = j*16;
  for (int idx = tid; idx < 64*64; idx += 256){
    int n = idx >> 6, ch = idx & 63;
    int R = (n >> 4)*512 + u0 + (n & 15);
    *(uint4*)&wlds[n*516 + ch*8] = *(const uint4*)&whh[(size_t)R*512 + ch*8];
  }
  __syncthreads();
  const int lane = tid & 63, wv = tid >> 6, fr = lane & 15, q = lane >> 4;
  const int m = tid >> 4, j2 = tid & 15;
  float cst = cbuf[(b0 + m)*512 + u0 + j2];
  unsigned* myslot = slots + g*64 + j;
  const unsigned* gslots = slots + g*64;
  unsigned short px0, px1, px2, px3;
  {
    size_t xi = ((size_t)(b0 + m)*48)*2048 + u0 + j2;
    px0 = xg[xi]; px1 = xg[xi + 512]; px2 = xg[xi + 1024]; px3 = xg[xi + 1536];
  }
  for (int t = 0; t < 48; ++t){
    const int rp = t & 1, wp = rp ^ 1;
    {
      const unsigned* hbu = hbuf + (size_t)rp*(64*256) + (size_t)b0*256;
      #pragma unroll
      for (int it = 0; it < 16; ++it){
        int idx = it*256 + tid;
        unsigned v = ldu(&hbu[idx]);
        int m2 = idx >> 8, u2 = idx & 255;
        *(unsigned*)&hblds[m2*516 + u2*2] = v;
      }
    }
    __syncthreads();
    f32x4 acc = {0.f,0.f,0.f,0.f};
    #pragma unroll
    for (int k0 = 0; k0 < 512; k0 += 32){
      bf16x8 av = *(const bf16x8*)&hblds[fr*516 + k0 + q*8];
      bf16x8 bv = *(const bf16x8*)&wlds[(wv*16 + fr)*516 + k0 + q*8];
      acc = __builtin_amdgcn_mfma_f32_16x16x32_bf16(av, bv, acc, 0,0,0);
    }
    #pragma unroll
    for (int r = 0; r < 4; ++r)
      gbufE[(q*4 + r)*68 + wv*16 + fr] = acc[r];
    __syncthreads();
    unsigned short hv;
    {
      float gi = gbufE[m*68 + j2]      + bf2f(px0);
      float gf = gbufE[m*68 + 16 + j2] + bf2f(px1);
      float gg = gbufE[m*68 + 32 + j2] + bf2f(px2);
      float go = gbufE[m*68 + 48 + j2] + bf2f(px3);
      float cc = sigm(gf)*cst + sigm(gi)*tanh2(gg);
      float hh = sigm(go)*tanh2(cc);
      cst = cc;
      hv = f2bf(hh);
      unsigned other = (unsigned)__shfl_xor((int)(unsigned)hv, 1);
      if ((j2 & 1) == 0)
        stu(&hbuf[(size_t)wp*(64*256) + (size_t)(b0+m)*256 + ((u0 + j2) >> 1)],
            ((unsigned)hv) | (other << 16));
    }
    VMWAIT();
    __syncthreads();
    if (tid == 0) stu(myslot, (unsigned)(t + 1));
    X[((size_t)t*64 + b0 + m)*1024 + u0 + j2] = hv;
    if (t < 47){
      size_t xi = ((size_t)(b0 + m)*48 + t + 1)*2048 + u0 + j2;
      px0 = xg[xi]; px1 = xg[xi + 512]; px2 = xg[xi + 1024]; px3 = xg[xi + 1536];
    }
    if (tid < 64){
      unsigned target = (unsigned)(t + 1);
      while (true){
        bool ok = true;
        for (int i = (int)tid; i < 32; i += 64)
          ok &= (ldu(&gslots[i]) >= target);
        if (__all(ok)) break;
        __builtin_amdgcn_s_sleep(1);
      }
    }
    __syncthreads();
  }
}

// ----------------------------- attention scores ----------------------------
// Block (b, lc): 64 l-rows x full k; ep tile in REGISTERS, reused for all 48 t.
__global__ __launch_bounds__(256) void attn_scores(
    const unsigned short* __restrict__ encpart, // [64*512][512]
    const float* __restrict__ hwh,              // [3072][512]
    const float* __restrict__ vvec,
    float* __restrict__ scores){                // [3072][512]
  __shared__ __align__(16) float hwhs[512];
  __shared__ __align__(16) float vm2s[512];
  __shared__ float red[4];
  const int tid = threadIdx.x;
  const int b = blockIdx.x >> 3, lc = blockIdx.x & 7;
  const int l = tid >> 2, kq = tid & 3;
  const int lane = tid & 63, wv = tid >> 6;
  vm2s[tid] = -2.f * vvec[tid];
  vm2s[tid+256] = -2.f * vvec[tid+256];
  __syncthreads();
  float vsumf;
  {
    float x = vm2s[tid] + vm2s[tid+256];
    #pragma unroll
    for (int off=32; off; off>>=1) x += __shfl_xor(x, off);
    if (lane == 0) red[wv] = x;
    __syncthreads();
    vsumf = -0.5f * (red[0]+red[1]+red[2]+red[3]);
  }
  bf16x8 epr[16];
  {
    const unsigned short* ep = encpart + ((size_t)(b*512 + lc*64 + l))*512 + kq*128;
    #pragma unroll
    for (int i = 0; i < 16; ++i) epr[i] = *(const bf16x8*)&ep[i*8];
  }
  const float C = 2.88539008f;
  for (int t = 0; t < 48; ++t){
    __syncthreads();
    hwhs[tid]     = C * hwh[((size_t)t*64 + b)*512 + tid];
    hwhs[tid+256] = C * hwh[((size_t)t*64 + b)*512 + tid + 256];
    __syncthreads();
    float sacc = 0.f;
    #pragma unroll
    for (int kk = 0; kk < 16; ++kk){
      float4 h0 = *(const float4*)&hwhs[kq*128 + kk*8];
      float4 h1 = *(const float4*)&hwhs[kq*128 + kk*8 + 4];
      float4 v0 = *(const float4*)&vm2s[kq*128 + kk*8];
      float4 v1 = *(const float4*)&vm2s[kq*128 + kk*8 + 4];
      const unsigned short* e = (const unsigned short*)&epr[kk];
      float hw[8] = {h0.x,h0.y,h0.z,h0.w,h1.x,h1.y,h1.z,h1.w};
      float vv[8] = {v0.x,v0.y,v0.z,v0.w,v1.x,v1.y,v1.z,v1.w};
      #pragma unroll
      for (int ee = 0; ee < 8; ++ee){
        float a = fmaf(bf2f(e[ee]), C, hw[ee]);
        sacc = fmaf(vv[ee], __builtin_amdgcn_rcpf(1.f + __builtin_amdgcn_exp2f(a)), sacc);
      }
    }
    sacc += __shfl_xor(sacc, 1);
    sacc += __shfl_xor(sacc, 2);
    if (kq == 0) scores[((size_t)t*64 + b)*512 + lc*64 + l] = vsumf + sacc;
  }
}

// ----------------------------- softmax -> aw (bf16) ------------------------
__global__ __launch_bounds__(256) void softmax_aw(
    const float* __restrict__ scores, unsigned short* __restrict__ awb){
  __shared__ float red[4];
  const int row = blockIdx.x, tid = threadIdx.x;
  const int lane = tid & 63, wv = tid >> 6;
  float v0 = scores[(size_t)row*512 + tid];
  float v1 = scores[(size_t)row*512 + tid + 256];
  float mx = fmaxf(v0, v1);
  #pragma unroll
  for (int off=32; off; off>>=1) mx = fmaxf(mx, __shfl_xor(mx, off));
  if (lane == 0) red[wv] = mx;
  __syncthreads();
  mx = fmaxf(fmaxf(red[0],red[1]), fmaxf(red[2],red[3]));
  __syncthreads();
  float e0 = __expf(v0 - mx), e1 = __expf(v1 - mx);
  float ps = e0 + e1;
  #pragma unroll
  for (int off=32; off; off>>=1) ps += __shfl_xor(ps, off);
  if (lane == 0) red[wv] = ps;
  __syncthreads();
  float inv = 1.f / (red[0]+red[1]+red[2]+red[3]);
  awb[(size_t)row*512 + tid]       = f2bf(e0 * inv);
  awb[(size_t)row*512 + tid + 256] = f2bf(e1 * inv);
}

// ----------------------------- ctx weighted sum ----------------------------
// Block (b, t-tile of 12). ctx[t][b][h] = sum_l aw[t*64+b][l]*encout[b][l][h];
// writes bf16 into X[(t*64+b)*1024 + 512 + h].
__global__ __launch_bounds__(256) void ctx_k(
    const unsigned short* __restrict__ awb,     // [3072][512]
    const unsigned short* __restrict__ encout,  // [64*512][512]
    unsigned short* __restrict__ X){
  __shared__ unsigned short awt[512*12];   // [l][tt]
  const int tid = threadIdx.x;
  const int b = blockIdx.x >> 2, t0 = (blockIdx.x & 3)*12;
  for (int i = tid; i < 12*256; i += 256){
    int tt = i >> 8, d = i & 255;
    unsigned u = *(const unsigned*)&awb[((size_t)(t0+tt)*64 + b)*512 + d*2];
    awt[(2*d)*12 + tt]   = (unsigned short)(u & 0xffffu);
    awt[(2*d+1)*12 + tt] = (unsigned short)(u >> 16);
  }
  __syncthreads();
  float a0[12], a1[12];
  #pragma unroll
  for (int j = 0; j < 12; ++j){ a0[j] = 0.f; a1[j] = 0.f; }
  const unsigned* eo = (const unsigned*)(encout + (size_t)b*512*512) + tid;
  for (int ll = 0; ll < 512; ++ll){
    unsigned ee = eo[(size_t)ll*256];
    float e0 = __uint_as_float((ee & 0xffffu) << 16);
    float e1 = __uint_as_float(ee & 0xffff0000u);
    const unsigned* wp2 = (const unsigned*)&awt[ll*12];
    float w[12];
    #pragma unroll
    for (int z = 0; z < 6; ++z){
      unsigned wu = wp2[z];
      w[2*z]   = bf2f((unsigned short)(wu & 0xffffu));
      w[2*z+1] = bf2f((unsigned short)(wu >> 16));
    }
    #pragma unroll
    for (int j = 0; j < 12; ++j){
      a0[j] = fmaf(w[j], e0, a0[j]);
      a1[j] = fmaf(w[j], e1, a1[j]);
    }
  }
  #pragma unroll
  for (int j = 0; j < 12; ++j){
    size_t r = (size_t)(t0+j)*64 + b;
    unsigned pk = ((unsigned)f2bf(a0[j])) | (((unsigned)f2bf(a1[j])) << 16);
    *(unsigned*)&X[r*1024 + 512 + 2*tid] = pk;
  }
}

// ----------------------------- projection ----------------------------------
__global__ void proj_k(const unsigned short* __restrict__ outs,
                       const float* __restrict__ pw, const float* __restrict__ pb,
                       float* __restrict__ out){
  int gid = blockIdx.x*256 + threadIdx.x;
  if (gid >= 64*48*7) return;
  int r = gid / 7, oc = gid % 7;
  int b = r & 63, t = r >> 6;
  const unsigned short* orow = outs + (size_t)r*512;
  const float* wrow = pw + oc*512;
  float s = pb[oc];
  for (int k = 0; k < 512; k += 8){
    bf16x8 o8 = *(const bf16x8*)&orow[k];
    #pragma unroll
    for (int e=0;e<8;e++) s += bf2f(((unsigned short*)&o8)[e]) * wrow[k+e];
  }
  out[((size_t)b*48 + t)*7 + oc] = s;
}

// ----------------------------- launch --------------------------------------
extern "C" void kernel_launch(void* const* d_in, const int* in_sizes, int n_in,
                              void* d_out, int out_size, void* d_ws, size_t ws_size,
                              hipStream_t stream){
  (void)in_sizes; (void)n_in; (void)out_size; (void)ws_size;
  const float* x_enc   = (const float*)d_in[0];
  const float* x_dec   = (const float*)d_in[1];
  const float* w_emb_e = (const float*)d_in[2];
  const float* w_emb_d = (const float*)d_in[3];
  const float* enc_Wih = (const float*)d_in[4];
  const float* enc_Whh = (const float*)d_in[5];
  const float* enc_b   = (const float*)d_in[6];
  const float* dec_Wih = (const float*)d_in[7];
  const float* dec_Whh = (const float*)d_in[8];
  const float* dec_b   = (const float*)d_in[9];
  const float* attn_W  = (const float*)d_in[10];
  const float* attn_b  = (const float*)d_in[11];
  const float* vvec    = (const float*)d_in[12];
  const float* fc_W    = (const float*)d_in[13];
  const float* fc_b    = (const float*)d_in[14];
  const float* proj_W  = (const float*)d_in[15];
  const float* proj_b  = (const float*)d_in[16];
  float* out = (float*)d_out;

  char* ws = (char*)d_ws;
  size_t off = 0;
  auto alloc = [&](size_t bytes)->char*{
    char* p = ws + off;
    off = (off + bytes + 255) & ~(size_t)255;
    return p;
  };
  unsigned short* encxw0 = (unsigned short*)alloc(128ull*64*2048*2);
  unsigned short* encxw1 = (unsigned short*)alloc(128ull*64*2048*2);
  unsigned short* encin  = (unsigned short*)alloc(512ull*64*512*2);  // embed; reused as enc_part
  unsigned short* encout = (unsigned short*)alloc(64ull*512*512*2);
  unsigned short* xs     = (unsigned short*)alloc(64ull*48*512*2);
  unsigned short* xg     = (unsigned short*)alloc(64ull*48*2048*2);
  unsigned short* Xb     = (unsigned short*)alloc(3072ull*1024*2);
  float* hwh    = (float*)alloc(3072ull*512*4);
  float* scores = (float*)alloc(3072ull*512*4);
  unsigned short* awb    = (unsigned short*)alloc(3072ull*512*2);
  unsigned short* outsb  = (unsigned short*)alloc(3072ull*512*2);
  unsigned short* wih_e  = (unsigned short*)alloc(2048ull*512*2);
  unsigned short* whh_e  = (unsigned short*)alloc(2048ull*512*2);
  unsigned short* wih_d  = (unsigned short*)alloc(2048ull*512*2);
  unsigned short* whh_d  = (unsigned short*)alloc(2048ull*512*2);
  unsigned short* whq    = (unsigned short*)alloc(512ull*512*2);
  unsigned short* weq    = (unsigned short*)alloc(512ull*512*2);
  unsigned short* fcw    = (unsigned short*)alloc(512ull*1024*2);
  unsigned* hbuf  = (unsigned*)alloc(2ull*64*256*4);
  float* cbuf   = (float*)alloc(64ull*512*4);
  unsigned* eslots = (unsigned*)alloc(4*64*4);
  unsigned* dslots = (unsigned*)alloc(4*64*4);

  hipMemsetAsync(eslots, 0, 4*64*4, stream);
  hipMemsetAsync(dslots, 0, 4*64*4, stream);
  hipMemsetAsync(hbuf, 0, 2ull*64*256*4, stream);
  hipMemsetAsync(cbuf, 0, 64ull*512*4, stream);

  cast_k<<<4096, 256, 0, stream>>>(enc_Wih, wih_e, 2048*512);
  cast_k<<<4096, 256, 0, stream>>>(enc_Whh, whh_e, 2048*512);
  cast_k<<<4096, 256, 0, stream>>>(dec_Wih, wih_d, 2048*512);
  cast_k<<<4096, 256, 0, stream>>>(dec_Whh, whh_d, 2048*512);
  cast_k<<<2048, 256, 0, stream>>>(fc_W, fcw, 512*1024);
  split_attn_k<<<1024, 256, 0, stream>>>(attn_W, whq, weq);

  embed_k<<<512, 512, 0, stream>>>(x_enc, w_emb_e, encin, 64, 512, 0, 512, 0);
  embed_k<<<64, 512, 0, stream>>>(x_dec, w_emb_d, xs, 64, 144, 48, 48, 1);

  // xg = xs @ dec_Wih^T + dec_b   [3072][2048]
  gemm_nt<<<dim3(16, 24), 256, 0, stream>>>(xs, 512, wih_d, 512, dec_b, xg, 2048, 3072, 2048, 512);

  // encoder: staging gemm per chunk (unfused), then persistent lstm
  unsigned short* xwb[2] = {encxw0, encxw1};
  for (int c = 0; c < 4; ++c){
    gemm_nt<<<dim3(16, 64), 256, 0, stream>>>(encin + (size_t)c*8192*512, 512, wih_e, 512,
                                              enc_b, xwb[c & 1], 2048, 8192, 2048, 512);
    lstm_enc<<<128, 256, 0, stream>>>(xwb[c & 1], whh_e, cbuf, hbuf, encout, c*128, 128, eslots);
  }

  // enc_part = encout @ We^T + attn_b  (reuses encin buffer)
  gemm_nt<<<dim3(4, 256), 256, 0, stream>>>(encout, 512, weq, 512, attn_b, encin, 512, 32768, 512, 512);

  // decoder LSTM h-sequence -> X[:, :512]
  dec_h<<<128, 256, 0, stream>>>(xg, whh_d, cbuf, hbuf, Xb, dslots);

  // hWh = h @ Wh^T  (f32)
  gemm_ntf<<<dim3(4, 24), 256, 0, stream>>>(Xb, 1024, whq, 512, hwh, 512, 3072, 512, 512);

  // scores, softmax, ctx
  attn_scores<<<512, 256, 0, stream>>>(encin /*enc_part*/, hwh, vvec, scores);
  softmax_aw<<<3072, 256, 0, stream>>>(scores, awb);
  ctx_k<<<256, 256, 0, stream>>>(awb, encout, Xb);

  // fc: [h|ctx] @ fc_W^T + fc_b
  gemm_nt<<<dim3(4, 24), 256, 0, stream>>>(Xb, 1024, fcw, 1024, fc_b, outsb, 512, 3072, 512, 1024);

  proj_k<<<84, 256, 0, stream>>>(outsb, proj_W, proj_b, out);
}